// Round 9
// baseline (414.893 us; speedup 1.0000x reference)
//
#include <hip/hip_runtime.h>
#include <hip/hip_bf16.h>

// GCN v8 — dis-prescaled activations kill per-edge dis loads.
//   Identity: agg[c] = dis[c] * (g[c] + sum g[r]),  g = dis ⊙ h  (bf16).
//   Gather inner loop: rows4 (sequential) + ONE random g-row load per edge,
//   pure adds, 16-deep unroll. Packed coarse-sort payload (row<<9|collo).
//   Producers store g = dis*h directly (k_linc, k_fused epilogue).

#define FDIM 64
#define NPART 8
#define GPB 32
#define NB 256
#define BW 512
#define MAXP 1024

typedef __hip_bfloat16 bf16;

// --- degree histogram by row, LDS-partitioned ---
__global__ void k_deg(const int* __restrict__ row, unsigned* __restrict__ part,
                      int E, int n, int psize) {
    __shared__ unsigned sh[12512];
    int p = blockIdx.x / GPB;
    int g = blockIdx.x % GPB;
    int base = p * psize;
    int lim = n - base; if (lim > psize) lim = psize;
    for (int i = threadIdx.x; i < lim; i += blockDim.x) sh[i] = 0u;
    __syncthreads();
    int stride = GPB * blockDim.x;
    for (int e = g * blockDim.x + threadIdx.x; e < E; e += stride) {
        int r = row[e] - base;
        if ((unsigned)r < (unsigned)lim) atomicAdd(&sh[r], 1u);
    }
    __syncthreads();
    unsigned* dst = part + ((size_t)p * GPB + g) * psize;
    for (int i = threadIdx.x; i < lim; i += blockDim.x) dst[i] = sh[i];
}

__global__ void k_dis(const unsigned* __restrict__ part, float* __restrict__ dis,
                      int n, int psize) {
    int i = blockIdx.x * blockDim.x + threadIdx.x;
    if (i >= n) return;
    int p = i / psize, loc = i - p * psize;
    const unsigned* src = part + (size_t)p * GPB * psize + loc;
    unsigned s = 0;
    #pragma unroll 8
    for (int g = 0; g < GPB; ++g) s += src[(size_t)g * psize];
    dis[i] = rsqrtf((float)s + 1.0f);
}

// --- coarse histogram ---
__global__ void k_chist(const int* __restrict__ col, int* __restrict__ M,
                        int E, int CH, int P) {
    __shared__ int h[MAXP];
    int b = blockIdx.x;
    for (int i = threadIdx.x; i < P; i += blockDim.x) h[i] = 0;
    __syncthreads();
    int s = b * CH, e = min(s + CH, E);
    for (int i = s + threadIdx.x; i < e; i += blockDim.x)
        atomicAdd(&h[col[i] >> 9], 1);
    __syncthreads();
    for (int p = threadIdx.x; p < P; p += blockDim.x)
        M[p * NB + b] = h[p];
}

// --- 3-phase parallel exclusive scan ---
__global__ void k_s1(int* __restrict__ M, int* __restrict__ bsum, int total) {
    __shared__ int tmp[256];
    int t = threadIdx.x;
    int i = blockIdx.x * 256 + t;
    int v = (i < total) ? M[i] : 0;
    tmp[t] = v;
    __syncthreads();
    for (int d = 1; d < 256; d <<= 1) {
        int u = (t >= d) ? tmp[t - d] : 0;
        __syncthreads();
        tmp[t] += u;
        __syncthreads();
    }
    if (i < total) M[i] = tmp[t] - v;
    if (t == 255) bsum[blockIdx.x] = tmp[255];
}

__global__ void k_s2(int* __restrict__ bsum, int nb) {
    __shared__ int tmp[256];
    int t = threadIdx.x;
    int v = (t < nb) ? bsum[t] : 0;
    tmp[t] = v;
    __syncthreads();
    for (int d = 1; d < 256; d <<= 1) {
        int u = (t >= d) ? tmp[t - d] : 0;
        __syncthreads();
        tmp[t] += u;
        __syncthreads();
    }
    if (t < nb) bsum[t] = tmp[t] - v;
}

__global__ void k_s3(int* __restrict__ M, const int* __restrict__ bsum,
                     int total, int E) {
    int i = blockIdx.x * 256 + threadIdx.x;
    if (i < total) M[i] += bsum[blockIdx.x];
    if (i == 0) M[total] = E;
}

// --- deterministic coarse scatter: s4[pos] = row<<9 | (col&511) ---
__global__ void k_cscatter(const int* __restrict__ row, const int* __restrict__ col,
                           const int* __restrict__ M, int* __restrict__ s4,
                           int E, int CH, int P) {
    __shared__ int cur[MAXP];
    int b = blockIdx.x;
    for (int p = threadIdx.x; p < P; p += blockDim.x) cur[p] = M[p * NB + b];
    __syncthreads();
    int s = b * CH, e = min(s + CH, E);
    for (int i = s + threadIdx.x; i < e; i += blockDim.x) {
        int r = row[i], c = col[i];
        int pos = atomicAdd(&cur[c >> 9], 1);
        s4[pos] = (r << 9) | (c & 511);
    }
}

// --- fine sort -> off[n+1], rows4[E] ---
__global__ void k_fsort(const int* __restrict__ s4, const int* __restrict__ M,
                        int* __restrict__ rows4, int* __restrict__ off,
                        int n, int E, int P) {
    __shared__ int hist[BW];
    __shared__ int loff[BW];
    __shared__ int tmp[256];
    int p = blockIdx.x, t = threadIdx.x;
    int gs = M[p * NB];
    int ge = (p + 1 < P) ? M[(p + 1) * NB] : E;
    int c0 = p << 9;
    int lim = n - c0; if (lim > BW) lim = BW;
    hist[2 * t] = 0; hist[2 * t + 1] = 0;
    __syncthreads();
    for (int i = gs + t; i < ge; i += 256)
        atomicAdd(&hist[s4[i] & 511], 1);
    __syncthreads();
    int s0 = hist[2 * t], s1 = hist[2 * t + 1];
    int ps = s0 + s1;
    tmp[t] = ps;
    __syncthreads();
    for (int d = 1; d < 256; d <<= 1) {
        int u = (t >= d) ? tmp[t - d] : 0;
        __syncthreads();
        tmp[t] += u;
        __syncthreads();
    }
    int ex = tmp[t] - ps;
    loff[2 * t] = ex;
    loff[2 * t + 1] = ex + s0;
    __syncthreads();
    for (int i = t; i < lim; i += 256) off[c0 + i] = gs + loff[i];
    if (p == P - 1 && t == 0) off[n] = E;
    __syncthreads();
    for (int i = gs + t; i < ge; i += 256) {
        int v = s4[i];
        int pos = gs + atomicAdd(&loff[v & 511], 1);
        rows4[pos] = v >> 9;
    }
}

// --- k1: g1(bf16) = dis ⊙ (concat(x,feat) @ W1 + b1) ---
__global__ __launch_bounds__(256, 4)
void k_linc(const float* __restrict__ x, const float* __restrict__ feat,
            const float* __restrict__ W, const float* __restrict__ b,
            const float* __restrict__ dis, bf16* __restrict__ out,
            int n, int nwaves) {
    __shared__ float sIn[4][FDIM];
    int t = threadIdx.x;
    int local = t >> 6, j = t & 63;
    float Wreg[FDIM];
    #pragma unroll
    for (int k = 0; k < FDIM; ++k) Wreg[k] = W[k * FDIM + j];   // column j
    float bj = b[j];
    int gw = blockIdx.x * 4 + local;
    for (int w = gw; w < n; w += nwaves) {
        sIn[local][j] = (j < 32) ? x[(size_t)w * 32 + j]
                                 : feat[(size_t)w * 32 + (j - 32)];
        __threadfence_block();
        float o = bj;
        #pragma unroll
        for (int k4 = 0; k4 < 16; ++k4) {
            float4 h4 = *(const float4*)&sIn[local][k4 * 4];
            o = fmaf(h4.x, Wreg[4 * k4 + 0], o);
            o = fmaf(h4.y, Wreg[4 * k4 + 1], o);
            o = fmaf(h4.z, Wreg[4 * k4 + 2], o);
            o = fmaf(h4.w, Wreg[4 * k4 + 3], o);
        }
        out[(size_t)w * FDIM + j] = __float2bfloat16(dis[w] * o);
        __threadfence_block();
    }
}

// --- fused: a = relu(dc*(g[w]+Σg[r])); o = a@W+b;
//     FINAL ? out=relu(o) fp32 : out=bf16(dis[w]*o) for next gather ---
template <bool FINAL>
__global__ __launch_bounds__(256, 4)
void k_fused(const int* __restrict__ rows4, const int* __restrict__ off,
             const float* __restrict__ dis, const bf16* __restrict__ g,
             const float* __restrict__ W, const float* __restrict__ b,
             void* __restrict__ outp, int n, int nwaves) {
    __shared__ float sIn[4][FDIM];
    int t = threadIdx.x;
    int local = t >> 6, j = t & 63;
    float Wreg[FDIM];
    #pragma unroll
    for (int k = 0; k < FDIM; ++k) Wreg[k] = W[k * FDIM + j];   // column j
    float bj = b[j];
    int gw = blockIdx.x * 4 + local;
    for (int w = gw; w < n; w += nwaves) {
        float dc = dis[w];
        float acc0 = __bfloat162float(g[(size_t)w * FDIM + j]);  // self loop
        float acc1 = 0.0f;
        int k = off[w], e = off[w + 1];
        for (; k + 16 <= e; k += 16) {
            int rr[16];
            #pragma unroll
            for (int u = 0; u < 16; ++u) rr[u] = rows4[k + u];
            float hv[16];
            #pragma unroll
            for (int u = 0; u < 16; ++u)
                hv[u] = __bfloat162float(g[(size_t)rr[u] * FDIM + j]);
            #pragma unroll
            for (int u = 0; u < 16; u += 2) { acc0 += hv[u]; acc1 += hv[u + 1]; }
        }
        for (; k + 4 <= e; k += 4) {
            int r0 = rows4[k], r1 = rows4[k + 1], r2 = rows4[k + 2], r3 = rows4[k + 3];
            float h0 = __bfloat162float(g[(size_t)r0 * FDIM + j]);
            float h1 = __bfloat162float(g[(size_t)r1 * FDIM + j]);
            float h2 = __bfloat162float(g[(size_t)r2 * FDIM + j]);
            float h3 = __bfloat162float(g[(size_t)r3 * FDIM + j]);
            acc0 += h0; acc1 += h1; acc0 += h2; acc1 += h3;
        }
        for (; k < e; ++k)
            acc0 += __bfloat162float(g[(size_t)rows4[k] * FDIM + j]);
        sIn[local][j] = fmaxf(dc * (acc0 + acc1), 0.0f);     // mid relu
        __threadfence_block();
        float o = bj;
        #pragma unroll
        for (int k4 = 0; k4 < 16; ++k4) {
            float4 h4 = *(const float4*)&sIn[local][k4 * 4];
            o = fmaf(h4.x, Wreg[4 * k4 + 0], o);
            o = fmaf(h4.y, Wreg[4 * k4 + 1], o);
            o = fmaf(h4.z, Wreg[4 * k4 + 2], o);
            o = fmaf(h4.w, Wreg[4 * k4 + 3], o);
        }
        if (FINAL) ((float*)outp)[(size_t)w * FDIM + j] = fmaxf(o, 0.0f);
        else       ((bf16*)outp)[(size_t)w * FDIM + j] = __float2bfloat16(dc * o);
        __threadfence_block();
    }
}

extern "C" void kernel_launch(void* const* d_in, const int* in_sizes, int n_in,
                              void* d_out, int out_size, void* d_ws, size_t ws_size,
                              hipStream_t stream) {
    const float* x    = (const float*)d_in[0];
    const float* feat = (const float*)d_in[1];
    const int*   ei   = (const int*)d_in[2];
    const float* W1   = (const float*)d_in[3];
    const float* b1   = (const float*)d_in[4];
    const float* W2   = (const float*)d_in[5];
    const float* b2   = (const float*)d_in[6];
    const float* Wfc  = (const float*)d_in[7];
    const float* bfc  = (const float*)d_in[8];
    float* out = (float*)d_out;

    const int n = in_sizes[0] / 32;   // 100000
    const int E = in_sizes[2] / 2;    // 1600000
    const int* row = ei;
    const int* col = ei + E;

    const int psize = (n + NPART - 1) / NPART;   // 12500
    const int P  = (n + BW - 1) / BW;            // 196
    const int CH = (E + NB - 1) / NB;            // 6250
    const int total = P * NB;                    // 50176
    const int nb1 = (total + 255) / 256;         // 196

    // ws (ints): off[n+1] | dis[n] | M[total+1] | bsum[256] | s4[E] | rows4[E]
    //            | bufA(bf16 64n) | bufB(bf16 64n)
    // part (NPART*GPB*psize u32 = 12.8 MB) aliases bufA+bufB (25.6 MB, consumed
    // by k_dis before any buf is written).
    int*   off  = (int*)d_ws;
    float* dis  = (float*)(off + (size_t)n + 1);
    int*   M    = (int*)(dis + n);
    int*   bsum = M + (size_t)total + 1;
    int*   s4    = bsum + 256;
    int*   rows4 = s4 + E;
    bf16*  bufA  = (bf16*)(rows4 + E);
    bf16*  bufB  = bufA + (size_t)n * FDIM;
    unsigned* part = (unsigned*)bufA;            // consumed before bufs written

    const int B = 256;
    const int GP = 2048;                          // persistent blocks
    const int NW = GP * 4;                        // wave stride

    // dis (deg by row)
    k_deg<<<NPART * GPB, B, 0, stream>>>(row, part, E, n, psize);
    k_dis<<<(n + B - 1) / B, B, 0, stream>>>(part, dis, n, psize);
    // CSR by col
    k_chist<<<NB, B, 0, stream>>>(col, M, E, CH, P);
    k_s1<<<nb1, B, 0, stream>>>(M, bsum, total);
    k_s2<<<1, B, 0, stream>>>(bsum, nb1);
    k_s3<<<nb1, B, 0, stream>>>(M, bsum, total, E);
    k_cscatter<<<NB, B, 0, stream>>>(row, col, M, s4, E, CH, P);
    k_fsort<<<P, B, 0, stream>>>(s4, M, rows4, off, n, E, P);

    // g1 = dis⊙(concat@W1+b1); g2 = dis⊙(relu(dis⊙agg)@W2+b2); out = relu(...)
    k_linc<<<GP, B, 0, stream>>>(x, feat, W1, b1, dis, bufA, n, NW);
    k_fused<false><<<GP, B, 0, stream>>>(rows4, off, dis, bufA, W2, b2, bufB, n, NW);
    k_fused<true><<<GP, B, 0, stream>>>(rows4, off, dis, bufB, Wfc, bfc, out, n, NW);
}